// Round 5
// baseline (752.846 us; speedup 1.0000x reference)
//
#include <hip/hip_runtime.h>
#include <stdint.h>

// ---------------------------------------------------------------------------
// Problem constants
// ---------------------------------------------------------------------------
#define V_VOCAB 50257
#define V_PAD2  50688          // 99 * 512 (col-groups of 512)
#define NGB     99             // col-groups per row of grid
#define NROWS   8192           // 4 * 2048
#define DIM     512
#define KTOP    10
#define MARGIN  0.3f           // >= 2 * (2^-7 * ||x|| * ||w||) worst case (~0.25)
#define ACH     8              // amb rows per W-scan pass

typedef __attribute__((ext_vector_type(8))) short  short8;
typedef __attribute__((ext_vector_type(4))) float  f32x4;

struct Ctrl { int mc; int namb; int hits; int pad_; };

// ws layout (bytes). Total ~60.7 MB.
#define OFF_WT2    0ULL
#define SZ_WT2     51904512ULL            // 50688*512*2, fragment-major layout
#define OFF_XC     (OFF_WT2 + SZ_WT2)
#define SZ_XC      8388608ULL             // 8192*512*2
#define OFF_BPAD   (OFF_XC + SZ_XC)
#define SZ_BPAD    (50688ULL*4)
#define OFF_ROWIDX (OFF_BPAD + SZ_BPAD)
#define OFF_THAT   (OFF_ROWIDX + 32768ULL)
#define OFF_COUNTS (OFF_THAT + 32768ULL)
#define OFF_AMB    (OFF_COUNTS + 32768ULL)
#define OFF_CTRL   (OFF_AMB + 32768ULL)
#define OFF_RK     (OFF_CTRL + 16ULL)
#define OFF_SST    (OFF_RK + 32768ULL)

#define GLOAD16(gp, lp) __builtin_amdgcn_global_load_lds( \
    (const __attribute__((address_space(1))) unsigned int*)(gp), \
    (__attribute__((address_space(3))) unsigned int*)(lp), 16, 0, 0)

__device__ __forceinline__ unsigned short f2bf(float f) {
  unsigned int u = __builtin_bit_cast(unsigned int, f);
  unsigned int r = (u + 0x7FFFu + ((u >> 16) & 1u)) >> 16;   // RNE
  return (unsigned short)r;
}
__device__ __forceinline__ float bf2f(unsigned short h) {
  unsigned int u = ((unsigned int)h) << 16;
  return __builtin_bit_cast(float, u);
}

// ---------------------------------------------------------------------------
// 1. prep: bpad (-1e30 on pad cols) + masked-row compaction
// ---------------------------------------------------------------------------
__global__ void k_prep(const int* __restrict__ mask, const float* __restrict__ b,
                       float* __restrict__ bpad, int* __restrict__ rowidx,
                       Ctrl* __restrict__ ctrl) {
  int i = blockIdx.x * 256 + threadIdx.x;
  if (i < V_PAD2) bpad[i] = (i < V_VOCAB) ? b[i] : -1e30f;
  if (i < NROWS && mask[i] != 0) {
    int p = atomicAdd(&ctrl->mc, 1);
    rowidx[p] = i;
  }
}

// ---------------------------------------------------------------------------
// 2. W f32[512][V] -> Wt2 bf16 FRAGMENT-MAJOR: chunk ci = cb*16+ks is 1KB;
//    byte lane*16+jj*2 in chunk = (col = cb*16 + (lane&15),
//                                  k   = ks*32 + (lane>>4)*8 + jj).
//    A wave's B-fragment load in k_count = one contiguous 1KB read.
// ---------------------------------------------------------------------------
__global__ void k_twt2(const float* __restrict__ W, unsigned short* __restrict__ Wt2) {
  const int wv = threadIdx.x >> 6, lane = threadIdx.x & 63;
  const int chunk = blockIdx.x * 4 + wv;           // 50688 chunks total
  const int cb = chunk >> 4, ks = chunk & 15;
  const int col = cb * 16 + (lane & 15);
  const int kb  = ks * 32 + (lane >> 4) * 8;
  short8 t;
#pragma unroll
  for (int jj = 0; jj < 8; ++jj) {
    float v = (col < V_VOCAB) ? W[(size_t)(kb + jj) * V_VOCAB + col] : 0.0f;
    t[jj] = (short)f2bf(v);
  }
  *(short8*)(Wt2 + (size_t)chunk * 512 + lane * 8) = t;
}

// ---------------------------------------------------------------------------
// 3. convert compacted x rows to bf16 (zero rows >= mc)
// ---------------------------------------------------------------------------
__global__ void k_xc(const float* __restrict__ x, const int* __restrict__ rowidx,
                     const Ctrl* __restrict__ ctrl, unsigned short* __restrict__ Xc) {
  const int wid = threadIdx.x >> 6, lane = threadIdx.x & 63;
  const int i = blockIdx.x * 4 + wid;
  const int mc = ctrl->mc;
  short8 t;
  if (i < mc) {
    const float* src = x + (size_t)rowidx[i] * DIM + lane * 8;
#pragma unroll
    for (int j = 0; j < 8; ++j) t[j] = (short)f2bf(src[j]);
  } else {
#pragma unroll
    for (int j = 0; j < 8; ++j) t[j] = 0;
  }
  *(short8*)(Xc + (size_t)i * DIM + lane * 8) = t;
}

// ---------------------------------------------------------------------------
// 4. per-row approx target score t_hat (bf16 dot, f32 accum; gathers W bf16
//    values from Wt2 fragment-major layout)
// ---------------------------------------------------------------------------
__global__ void k_that(const unsigned short* __restrict__ Xc,
                       const unsigned short* __restrict__ Wt2,
                       const float* __restrict__ bpad,
                       const int* __restrict__ rowidx, const int* __restrict__ target,
                       const Ctrl* __restrict__ ctrl, float* __restrict__ that) {
  const int wid = threadIdx.x >> 6, lane = threadIdx.x & 63;
  const int i = blockIdx.x * 4 + wid;
  const int mc = ctrl->mc;
  if (i >= mc) { if (lane == 0) that[i] = 1e30f; return; }
  const int tg = target[rowidx[i]];
  const int cb = tg >> 4, cl = tg & 15;
  // lane covers k = lane*8 .. +7:  ks = lane>>2, k8grp = lane&3
  const size_t u16 = ((size_t)(cb * 16 + (lane >> 2)) * 64 + (lane & 3) * 16 + cl);
  short8 xa = *(const short8*)(Xc + (size_t)i * DIM + lane * 8);
  short8 wa = *(const short8*)(Wt2 + u16 * 8);
  float s = 0.f;
#pragma unroll
  for (int j = 0; j < 8; ++j)
    s += bf2f((unsigned short)xa[j]) * bf2f((unsigned short)wa[j]);
#pragma unroll
  for (int d = 1; d < 64; d <<= 1) s += __shfl_xor(s, d, 64);
  if (lane == 0) that[i] = s + bpad[tg];
}

// ---------------------------------------------------------------------------
// 5. fused GEMM-count, BARRIER-FREE: A (128x512, full K) resident in LDS
//    (XOR slot swizzle via pre-swizzled gload source); B streamed from
//    fragment-major Wt2 by perfectly-coalesced 1KB reg loads, prefetch
//    depth 2. 8 waves x 64 cols, 16 k-steps, no sync in the loop.
// ---------------------------------------------------------------------------
__launch_bounds__(512, 2)
__global__ void k_count(const unsigned short* __restrict__ Xc,
                        const unsigned short* __restrict__ Wt2,
                        const float* __restrict__ bpad, const float* __restrict__ that,
                        const Ctrl* __restrict__ ctrl, unsigned int* __restrict__ counts) {
  const int mc = ctrl->mc;
  const int mbase = blockIdx.y * 128;
  if (mbase >= mc) return;
  const int nb = blockIdx.x;                 // col-group of 512

  __shared__ unsigned short sA[65536];       // 128 KB: [row 128][64 slots of 16B]
  __shared__ float thr[128];

  const int tid  = threadIdx.x;
  const int lane = tid & 63;
  const int w    = tid >> 6;

  // ---- A fill: 16 chunks x 8KB, linear LDS dest, inverse-swizzled source
  {
    const int r0 = tid >> 6;                          // row = ch*8 + r0
    const int sl = (tid & 63) ^ (r0 & 7);             // logical slot for phys (tid&63)
    const char* src0 = (const char*)Xc + (((size_t)(mbase + r0)) << 10) + sl * 16;
    char* dst0 = (char*)sA + tid * 16;
#pragma unroll
    for (int ch = 0; ch < 16; ++ch)
      GLOAD16(src0 + (size_t)ch * 8192, dst0 + ch * 8192);
  }
  if (tid < 128) thr[tid] = that[mbase + tid];
  __syncthreads();   // drains the gload_lds; the ONLY barrier in this kernel

  // ---- main loop: per wave, cols w*64..+63 (4 cb blocks), 16 k-steps
  const char* Bp = (const char*)Wt2 + ((size_t)(nb * 32 + w * 4) << 14);  // *16KB
  const int fr = lane & 15;
  const int fq = lane >> 4;

  f32x4 acc[8][4];
#pragma unroll
  for (int a = 0; a < 8; ++a)
#pragma unroll
    for (int c = 0; c < 4; ++c) acc[a][c] = (f32x4)0.0f;

  short8 bq[3][4];
#pragma unroll
  for (int j = 0; j < 4; ++j) {
    bq[0][j] = *(const short8*)(Bp + j * 16384 + 0 * 1024 + lane * 16);
    bq[1][j] = *(const short8*)(Bp + j * 16384 + 1 * 1024 + lane * 16);
  }

#pragma unroll
  for (int ks = 0; ks < 16; ++ks) {
    if (ks + 2 < 16) {
#pragma unroll
      for (int j = 0; j < 4; ++j)
        bq[(ks + 2) % 3][j] =
            *(const short8*)(Bp + j * 16384 + (ks + 2) * 1024 + lane * 16);
    }
#pragma unroll
    for (int mb = 0; mb < 8; ++mb) {
      const int row = mb * 16 + fr;
      const int phys = (ks * 4 + fq) ^ (fr & 7);
      short8 a = *(const short8*)((const char*)sA + row * 1024 + phys * 16);
#pragma unroll
      for (int j = 0; j < 4; ++j)
        acc[mb][j] = __builtin_amdgcn_mfma_f32_16x16x32_bf16(
            a, bq[ks % 3][j], acc[mb][j], 0, 0, 0);
    }
  }

  // ---- epilogue (per-wave, no barrier): compare + pack + reduce + atomics
  float bv[4];
#pragma unroll
  for (int j = 0; j < 4; ++j)
    bv[j] = bpad[nb * 512 + w * 64 + j * 16 + fr];

#pragma unroll
  for (int mb = 0; mb < 8; ++mb) {
#pragma unroll
    for (int r = 0; r < 4; ++r) {
      const float th  = thr[mb * 16 + fq * 4 + r];
      const float tlo = th - MARGIN, thi = th + MARGIN;
      unsigned int p = 0;
#pragma unroll
      for (int j = 0; j < 4; ++j) {
        const float s = acc[mb][j][r] + bv[j];
        p += (s > tlo) ? 1u : 0u;
        p += (s > thi) ? (1u << 16) : 0u;
      }
      int pi = (int)p;
#pragma unroll
      for (int d = 1; d < 16; d <<= 1) pi += __shfl_xor(pi, d, 64);
      if ((lane & 15) == 0)
        atomicAdd(&counts[mbase + mb * 16 + fq * 4 + r], (unsigned int)pi);
    }
  }
}

// ---------------------------------------------------------------------------
// 6. decide: certain hit / certain miss / ambiguous
// ---------------------------------------------------------------------------
__global__ void k_decide(const unsigned int* __restrict__ counts,
                         Ctrl* __restrict__ ctrl, int* __restrict__ amb) {
  const int i = blockIdx.x * 256 + threadIdx.x;
  if (i >= ctrl->mc) return;
  const unsigned int c = counts[i];
  const unsigned int lo = c & 0xFFFFu, hi = c >> 16;
  if (lo <= KTOP - 1) { atomicAdd(&ctrl->hits, 1); }
  else if (hi >= KTOP) { /* certain miss */ }
  else { int p = atomicAdd(&ctrl->namb, 1); amb[p] = i; }
}

// ---------------------------------------------------------------------------
// 7a. fixup targets (exact f32, sequential fmaf chain — must match k_fixscan)
// ---------------------------------------------------------------------------
__global__ void k_fixt(const float* __restrict__ x, const float* __restrict__ W,
                       const float* __restrict__ b, const int* __restrict__ rowidx,
                       const int* __restrict__ target, const int* __restrict__ amb,
                       const Ctrl* __restrict__ ctrl, float* __restrict__ sst) {
  const int a = blockIdx.x * 64 + threadIdx.x;
  if (a >= ctrl->namb) return;
  const int n = rowidx[amb[a]];
  const int tg = target[n];
  float st = 0.f;
  for (int k = 0; k < DIM; ++k)
    st = fmaf(x[(size_t)n * DIM + k], W[(size_t)k * V_VOCAB + tg], st);
  sst[a] = st + b[tg];
}

// ---------------------------------------------------------------------------
// 7b. fixup scan: one coalesced streaming pass over W for <=ACH rows at a time
// ---------------------------------------------------------------------------
__global__ void k_fixscan(const float* __restrict__ x, const float* __restrict__ W,
                          const float* __restrict__ b, const int* __restrict__ rowidx,
                          const int* __restrict__ target, const int* __restrict__ amb,
                          const float* __restrict__ sst, const Ctrl* __restrict__ ctrl,
                          int* __restrict__ rk) {
  __shared__ float sx[ACH][DIM];
  const int j = blockIdx.x * 256 + threadIdx.x;
  const int namb = ctrl->namb;
  const float bj = (j < V_VOCAB) ? b[j] : 0.f;
  for (int base = 0; base < namb; base += ACH) {
    __syncthreads();
    for (int t = threadIdx.x; t < ACH * DIM / 4; t += 256) {
      const int a  = t / (DIM / 4);
      const int kk = (t % (DIM / 4)) * 4;
      f32x4 v = (f32x4)0.f;
      if (base + a < namb) {
        const int n = rowidx[amb[base + a]];
        v = *(const f32x4*)(x + (size_t)n * DIM + kk);
      }
      *(f32x4*)(&sx[a][kk]) = v;
    }
    __syncthreads();
    if (j >= V_VOCAB) continue;
    float s[ACH];
#pragma unroll
    for (int a = 0; a < ACH; ++a) s[a] = 0.f;
    for (int k = 0; k < DIM; ++k) {
      const float wv = W[(size_t)k * V_VOCAB + j];
#pragma unroll
      for (int a = 0; a < ACH; ++a) s[a] = fmaf(sx[a][k], wv, s[a]);
    }
#pragma unroll
    for (int a = 0; a < ACH; ++a) {
      if (base + a < namb) {
        const int tg = target[rowidx[amb[base + a]]];
        const float sc = s[a] + bj;
        const float st = sst[base + a];
        if (sc > st || (sc == st && j < tg)) atomicAdd(&rk[base + a], 1);
      }
    }
  }
}

// ---------------------------------------------------------------------------
// 7c. fixup decide
// ---------------------------------------------------------------------------
__global__ void k_fixdec(const int* __restrict__ rk, Ctrl* __restrict__ ctrl) {
  const int a = blockIdx.x * 256 + threadIdx.x;
  if (a < ctrl->namb && rk[a] <= KTOP - 1) atomicAdd(&ctrl->hits, 1);
}

// ---------------------------------------------------------------------------
// 8. finalize
// ---------------------------------------------------------------------------
__global__ void k_final(const Ctrl* __restrict__ ctrl, float* __restrict__ out) {
  out[0] = (float)ctrl->hits / (float)ctrl->mc;
}

// ---------------------------------------------------------------------------
extern "C" void kernel_launch(void* const* d_in, const int* in_sizes, int n_in,
                              void* d_out, int out_size, void* d_ws, size_t ws_size,
                              hipStream_t stream) {
  const float* x      = (const float*)d_in[0];   // [8192, 512]
  const int*   target = (const int*)d_in[1];     // [8192]
  const int*   mask   = (const int*)d_in[2];     // [8192]
  const float* W      = (const float*)d_in[3];   // [512, 50257]
  const float* b      = (const float*)d_in[4];   // [50257]
  float* out = (float*)d_out;

  char* ws = (char*)d_ws;
  unsigned short* Wt2    = (unsigned short*)(ws + OFF_WT2);
  unsigned short* Xc     = (unsigned short*)(ws + OFF_XC);
  float*          bpad   = (float*)(ws + OFF_BPAD);
  int*            rowidx = (int*)(ws + OFF_ROWIDX);
  float*          that   = (float*)(ws + OFF_THAT);
  unsigned int*   counts = (unsigned int*)(ws + OFF_COUNTS);
  int*            amb    = (int*)(ws + OFF_AMB);
  Ctrl*           ctrl   = (Ctrl*)(ws + OFF_CTRL);
  int*            rk     = (int*)(ws + OFF_RK);
  float*          sst    = (float*)(ws + OFF_SST);

  // zero counts + amb + ctrl + rk (contiguous region)
  hipMemsetAsync(ws + OFF_COUNTS, 0, 32768 + 32768 + 16 + 32768, stream);

  k_prep   <<<198, 256, 0, stream>>>(mask, b, bpad, rowidx, ctrl);
  k_twt2   <<<12672, 256, 0, stream>>>(W, Wt2);
  k_xc     <<<2048, 256, 0, stream>>>(x, rowidx, ctrl, Xc);
  k_that   <<<2048, 256, 0, stream>>>(Xc, Wt2, bpad, rowidx, target, ctrl, that);
  k_count  <<<dim3(NGB, 64), 512, 0, stream>>>(Xc, Wt2, bpad, that, ctrl, counts);
  k_decide <<<32, 256, 0, stream>>>(counts, ctrl, amb);
  k_fixt   <<<128, 64, 0, stream>>>(x, W, b, rowidx, target, amb, ctrl, sst);
  k_fixscan<<<197, 256, 0, stream>>>(x, W, b, rowidx, target, amb, sst, ctrl, rk);
  k_fixdec <<<32, 256, 0, stream>>>(rk, ctrl);
  k_final  <<<1, 1, 0, stream>>>(ctrl, out);
}

// Round 6
// 668.393 us; speedup vs baseline: 1.1264x; 1.1264x over previous
//
#include <hip/hip_runtime.h>
#include <stdint.h>

// ---------------------------------------------------------------------------
// Problem constants
// ---------------------------------------------------------------------------
#define V_VOCAB 50257
#define V_PAD   50432          // 394 * 128
#define NTB     394            // N tiles of 128
#define NROWS   8192           // 4 * 2048
#define DIM     512
#define KTOP    10
#define MARGIN  0.3f           // >= 2 * (2^-7 * ||x|| * ||w||) worst case (~0.25)
#define ACH     8              // amb rows per W-scan pass

typedef __attribute__((ext_vector_type(8))) short  short8;
typedef __attribute__((ext_vector_type(4))) float  f32x4;

struct Ctrl { int mc; int namb; int hits; int pad_; };

// ws layout (bytes). Total ~60.4 MB.
#define OFF_WT     0ULL
#define SZ_WT      51642368ULL            // 50432*512*2
#define OFF_XC     (OFF_WT + SZ_WT)
#define SZ_XC      8388608ULL             // 8192*512*2
#define OFF_BPAD   (OFF_XC + SZ_XC)
#define SZ_BPAD    (50432ULL*4)
#define OFF_ROWIDX (OFF_BPAD + SZ_BPAD)
#define OFF_THAT   (OFF_ROWIDX + 32768ULL)
#define OFF_COUNTS (OFF_THAT + 32768ULL)
#define OFF_AMB    (OFF_COUNTS + 32768ULL)
#define OFF_CTRL   (OFF_AMB + 32768ULL)
#define OFF_RK     (OFF_CTRL + 16ULL)
#define OFF_SST    (OFF_RK + 32768ULL)

#define GLOAD16(gp, lp) __builtin_amdgcn_global_load_lds( \
    (const __attribute__((address_space(1))) unsigned int*)(gp), \
    (__attribute__((address_space(3))) unsigned int*)(lp), 16, 0, 0)

#define SBAR()  do { asm volatile("" ::: "memory"); __builtin_amdgcn_s_barrier(); \
                     asm volatile("" ::: "memory"); } while (0)
#define VM6()   asm volatile("s_waitcnt vmcnt(6)" ::: "memory")
#define VM0()   asm volatile("s_waitcnt vmcnt(0)" ::: "memory")

__device__ __forceinline__ unsigned short f2bf(float f) {
  unsigned int u = __builtin_bit_cast(unsigned int, f);
  unsigned int r = (u + 0x7FFFu + ((u >> 16) & 1u)) >> 16;   // RNE
  return (unsigned short)r;
}
__device__ __forceinline__ float bf2f(unsigned short h) {
  unsigned int u = ((unsigned int)h) << 16;
  return __builtin_bit_cast(float, u);
}

// ---------------------------------------------------------------------------
// 1. prep
// ---------------------------------------------------------------------------
__global__ void k_prep(const int* __restrict__ mask, const float* __restrict__ b,
                       float* __restrict__ bpad, int* __restrict__ rowidx,
                       Ctrl* __restrict__ ctrl) {
  int i = blockIdx.x * 256 + threadIdx.x;
  if (i < V_PAD) bpad[i] = (i < V_VOCAB) ? b[i] : -1e30f;
  if (i < NROWS && mask[i] != 0) {
    int p = atomicAdd(&ctrl->mc, 1);
    rowidx[p] = i;
  }
}

// ---------------------------------------------------------------------------
// 2. transpose+convert: W f32[512][V] -> Wt bf16[V_PAD][512]
// ---------------------------------------------------------------------------
__global__ void k_twt(const float* __restrict__ W, unsigned short* __restrict__ Wt) {
  __shared__ float lt[64][65];
  const int vbase = blockIdx.x * 64;
  const int kbase = blockIdx.y * 64;
  const int tid = threadIdx.x;
  const int krow = tid >> 6;
  const int col  = tid & 63;
  const int v    = vbase + col;
#pragma unroll
  for (int rr = 0; rr < 16; ++rr) {
    int kl = krow + rr * 4;
    float val = (v < V_VOCAB) ? W[(size_t)(kbase + kl) * V_VOCAB + v] : 0.0f;
    lt[kl][col] = val;
  }
  __syncthreads();
  const int vr = tid >> 3;
  const int kc = tid & 7;
#pragma unroll
  for (int p = 0; p < 2; ++p) {
    int vl = p * 32 + vr;
    short8 t;
#pragma unroll
    for (int j = 0; j < 8; ++j) t[j] = (short)f2bf(lt[kc * 8 + j][vl]);
    *(short8*)(Wt + (size_t)(vbase + vl) * DIM + kbase + kc * 8) = t;
  }
}

// ---------------------------------------------------------------------------
// 3. convert compacted x rows to bf16
// ---------------------------------------------------------------------------
__global__ void k_xc(const float* __restrict__ x, const int* __restrict__ rowidx,
                     const Ctrl* __restrict__ ctrl, unsigned short* __restrict__ Xc) {
  const int wid = threadIdx.x >> 6, lane = threadIdx.x & 63;
  const int i = blockIdx.x * 4 + wid;
  const int mc = ctrl->mc;
  short8 t;
  if (i < mc) {
    const float* src = x + (size_t)rowidx[i] * DIM + lane * 8;
#pragma unroll
    for (int j = 0; j < 8; ++j) t[j] = (short)f2bf(src[j]);
  } else {
#pragma unroll
    for (int j = 0; j < 8; ++j) t[j] = 0;
  }
  *(short8*)(Xc + (size_t)i * DIM + lane * 8) = t;
}

// ---------------------------------------------------------------------------
// 4. per-row approx target score t_hat
// ---------------------------------------------------------------------------
__global__ void k_that(const unsigned short* __restrict__ Xc,
                       const unsigned short* __restrict__ Wt,
                       const float* __restrict__ bpad,
                       const int* __restrict__ rowidx, const int* __restrict__ target,
                       const Ctrl* __restrict__ ctrl, float* __restrict__ that) {
  const int wid = threadIdx.x >> 6, lane = threadIdx.x & 63;
  const int i = blockIdx.x * 4 + wid;
  const int mc = ctrl->mc;
  if (i >= mc) { if (lane == 0) that[i] = 1e30f; return; }
  const int tg = target[rowidx[i]];
  short8 xa = *(const short8*)(Xc + (size_t)i * DIM + lane * 8);
  short8 wa = *(const short8*)(Wt + (size_t)tg * DIM + lane * 8);
  float s = 0.f;
#pragma unroll
  for (int j = 0; j < 8; ++j)
    s += bf2f((unsigned short)xa[j]) * bf2f((unsigned short)wa[j]);
#pragma unroll
  for (int d = 1; d < 64; d <<= 1) s += __shfl_xor(s, d, 64);
  if (lane == 0) that[i] = s + bpad[tg];
}

// ---------------------------------------------------------------------------
// 5. fused GEMM-count: 256x128 tile, BK=64, THREE LDS buffers, 1 barrier and
//    1 counted vmcnt(6) per K-tile. Stage for K-tile t+2 is issued at
//    iteration t -> issue-to-wait distance = 2 K-tile computes (~2500 cyc),
//    structurally covering HBM latency. 8 waves (4M x 2N), per-wave 64x64.
//    XOR slot swizzle via pre-swizzled global source (proven 0-conflict).
// ---------------------------------------------------------------------------
__launch_bounds__(512, 2)
__global__ void k_count(const unsigned short* __restrict__ Xc,
                        const unsigned short* __restrict__ Wt,
                        const float* __restrict__ bpad, const float* __restrict__ that,
                        const Ctrl* __restrict__ ctrl, unsigned int* __restrict__ counts) {
  const int mc = ctrl->mc;
  const int mbase = blockIdx.y * 256;
  if (mbase >= mc) return;
  const int nbase = blockIdx.x * 128;

  __shared__ char lds[147456];     // 3 buffers x (A 32KB + B 16KB)

  const int tid  = threadIdx.x;
  const int lane = tid & 63;
  const int w    = tid >> 6;
  const int wr   = w >> 1;         // 0..3 : A row block (64 rows)
  const int wc   = w & 1;          // 0..1 : B col block (64 cols)

  const char* Ag = (const char*)Xc + (size_t)mbase * 1024;   // row stride 1024B
  const char* Bg = (const char*)Wt + (size_t)nbase * 1024;
  const int sws  = ((tid & 7) ^ ((tid >> 3) & 7)) * 16;      // pre-swizzled src slot
  const int r8   = tid >> 3;                                 // row within 64-group
  const int dst0 = tid * 16;

  // stage one K-tile (kt) into buffer q: A rows 0..255, B rows 0..127
#define STAGE(q, kt) do {                                                      \
    const size_t _kb = (size_t)(kt) * 128;                                     \
    _Pragma("unroll") for (int _c = 0; _c < 4; ++_c)                           \
      GLOAD16(Ag + (size_t)(_c * 64 + r8) * 1024 + _kb + sws,                  \
              lds + (q) * 49152 + _c * 8192 + dst0);                           \
    _Pragma("unroll") for (int _c = 0; _c < 2; ++_c)                           \
      GLOAD16(Bg + (size_t)(_c * 64 + r8) * 1024 + _kb + sws,                  \
              lds + (q) * 49152 + 32768 + _c * 8192 + dst0);                   \
  } while (0)

  const int fr = lane & 15;
  const int fq = lane >> 4;
  const int p0 = ((fq) ^ (fr & 7)) * 16;        // phys byte slot, k-slot 0
  const int p1 = ((4 + fq) ^ (fr & 7)) * 16;    // k-slot 1

  f32x4 acc[4][4];
#pragma unroll
  for (int a = 0; a < 4; ++a)
#pragma unroll
    for (int c = 0; c < 4; ++c) acc[a][c] = (f32x4)0.0f;

  // compute one K-tile from buffer q (ds_read/MFMA interleave left to compiler)
#define KTILE(q) do {                                                          \
    const char* _ab = lds + (q) * 49152;                                       \
    const char* _bb = _ab + 32768;                                             \
    _Pragma("unroll") for (int _ks = 0; _ks < 2; ++_ks) {                      \
      const int _p = _ks ? p1 : p0;                                            \
      short8 a4[4], b4[4];                                                     \
      _Pragma("unroll") for (int _i = 0; _i < 4; ++_i)                         \
        a4[_i] = *(const short8*)(_ab + (wr * 64 + _i * 16 + fr) * 128 + _p);  \
      _Pragma("unroll") for (int _i = 0; _i < 4; ++_i)                         \
        b4[_i] = *(const short8*)(_bb + (wc * 64 + _i * 16 + fr) * 128 + _p);  \
      __builtin_amdgcn_s_setprio(1);                                           \
      _Pragma("unroll") for (int _m = 0; _m < 4; ++_m)                         \
      _Pragma("unroll") for (int _n = 0; _n < 4; ++_n)                         \
        acc[_m][_n] = __builtin_amdgcn_mfma_f32_16x16x32_bf16(                 \
            a4[_m], b4[_n], acc[_m][_n], 0, 0, 0);                             \
      __builtin_amdgcn_s_setprio(0);                                           \
    }                                                                          \
  } while (0)

  // prologue: two K-tiles in flight
  STAGE(0, 0);
  STAGE(1, 1);

#pragma unroll
  for (int t = 0; t < 8; ++t) {
    VM6();        // buffer t%3 (staged at t-2) fully landed; <=1 stage in flight
    SBAR();       // all waves' stages visible; prev-iter reads all retired
    STAGE((t + 2) % 3, (t + 2 < 8) ? (t + 2) : 7);   // clamp tail (unused)
    KTILE(t % 3);
  }
  VM0();          // drain tail stages before LDS dealloc / epilogue

  // epilogue: compare + pack + 16-lane reduce + atomics
  float bv[4];
#pragma unroll
  for (int ni = 0; ni < 4; ++ni)
    bv[ni] = bpad[nbase + wc * 64 + ni * 16 + fr];

#pragma unroll
  for (int mi = 0; mi < 4; ++mi) {
#pragma unroll
    for (int r = 0; r < 4; ++r) {
      const int m = mbase + wr * 64 + mi * 16 + fq * 4 + r;
      const float th  = that[m];
      const float tlo = th - MARGIN, thi = th + MARGIN;
      unsigned int p = 0;
#pragma unroll
      for (int ni = 0; ni < 4; ++ni) {
        const float s = acc[mi][ni][r] + bv[ni];
        p += (s > tlo) ? 1u : 0u;
        p += (s > thi) ? (1u << 16) : 0u;
      }
      int pi = (int)p;
#pragma unroll
      for (int d = 1; d < 16; d <<= 1) pi += __shfl_xor(pi, d, 64);
      if ((lane & 15) == 0) atomicAdd(&counts[m], (unsigned int)pi);
    }
  }
#undef STAGE
#undef KTILE
}

// ---------------------------------------------------------------------------
// 6. decide
// ---------------------------------------------------------------------------
__global__ void k_decide(const unsigned int* __restrict__ counts,
                         Ctrl* __restrict__ ctrl, int* __restrict__ amb) {
  const int i = blockIdx.x * 256 + threadIdx.x;
  if (i >= ctrl->mc) return;
  const unsigned int c = counts[i];
  const unsigned int lo = c & 0xFFFFu, hi = c >> 16;
  if (lo <= KTOP - 1) { atomicAdd(&ctrl->hits, 1); }
  else if (hi >= KTOP) { /* certain miss */ }
  else { int p = atomicAdd(&ctrl->namb, 1); amb[p] = i; }
}

// ---------------------------------------------------------------------------
// 7a. fixup targets (exact f32, sequential fmaf chain — must match k_fixscan)
// ---------------------------------------------------------------------------
__global__ void k_fixt(const float* __restrict__ x, const float* __restrict__ W,
                       const float* __restrict__ b, const int* __restrict__ rowidx,
                       const int* __restrict__ target, const int* __restrict__ amb,
                       const Ctrl* __restrict__ ctrl, float* __restrict__ sst) {
  const int a = blockIdx.x * 64 + threadIdx.x;
  if (a >= ctrl->namb) return;
  const int n = rowidx[amb[a]];
  const int tg = target[n];
  float st = 0.f;
  for (int k = 0; k < DIM; ++k)
    st = fmaf(x[(size_t)n * DIM + k], W[(size_t)k * V_VOCAB + tg], st);
  sst[a] = st + b[tg];
}

// ---------------------------------------------------------------------------
// 7b. fixup scan: one coalesced streaming pass over W for <=ACH rows at a time
// ---------------------------------------------------------------------------
__global__ void k_fixscan(const float* __restrict__ x, const float* __restrict__ W,
                          const float* __restrict__ b, const int* __restrict__ rowidx,
                          const int* __restrict__ target, const int* __restrict__ amb,
                          const float* __restrict__ sst, const Ctrl* __restrict__ ctrl,
                          int* __restrict__ rk) {
  __shared__ float sx[ACH][DIM];
  const int j = blockIdx.x * 256 + threadIdx.x;
  const int namb = ctrl->namb;
  const float bj = (j < V_VOCAB) ? b[j] : 0.f;
  for (int base = 0; base < namb; base += ACH) {
    __syncthreads();
    for (int t = threadIdx.x; t < ACH * DIM / 4; t += 256) {
      const int a  = t / (DIM / 4);
      const int kk = (t % (DIM / 4)) * 4;
      f32x4 v = (f32x4)0.f;
      if (base + a < namb) {
        const int n = rowidx[amb[base + a]];
        v = *(const f32x4*)(x + (size_t)n * DIM + kk);
      }
      *(f32x4*)(&sx[a][kk]) = v;
    }
    __syncthreads();
    if (j >= V_VOCAB) continue;
    float s[ACH];
#pragma unroll
    for (int a = 0; a < ACH; ++a) s[a] = 0.f;
    for (int k = 0; k < DIM; ++k) {
      const float wv = W[(size_t)k * V_VOCAB + j];
#pragma unroll
      for (int a = 0; a < ACH; ++a) s[a] = fmaf(sx[a][k], wv, s[a]);
    }
#pragma unroll
    for (int a = 0; a < ACH; ++a) {
      if (base + a < namb) {
        const int tg = target[rowidx[amb[base + a]]];
        const float sc = s[a] + bj;
        const float st = sst[base + a];
        if (sc > st || (sc == st && j < tg)) atomicAdd(&rk[base + a], 1);
      }
    }
  }
}

// ---------------------------------------------------------------------------
// 7c. fixup decide
// ---------------------------------------------------------------------------
__global__ void k_fixdec(const int* __restrict__ rk, Ctrl* __restrict__ ctrl) {
  const int a = blockIdx.x * 256 + threadIdx.x;
  if (a < ctrl->namb && rk[a] <= KTOP - 1) atomicAdd(&ctrl->hits, 1);
}

// ---------------------------------------------------------------------------
// 8. finalize
// ---------------------------------------------------------------------------
__global__ void k_final(const Ctrl* __restrict__ ctrl, float* __restrict__ out) {
  out[0] = (float)ctrl->hits / (float)ctrl->mc;
}

// ---------------------------------------------------------------------------
extern "C" void kernel_launch(void* const* d_in, const int* in_sizes, int n_in,
                              void* d_out, int out_size, void* d_ws, size_t ws_size,
                              hipStream_t stream) {
  const float* x      = (const float*)d_in[0];   // [8192, 512]
  const int*   target = (const int*)d_in[1];     // [8192]
  const int*   mask   = (const int*)d_in[2];     // [8192]
  const float* W      = (const float*)d_in[3];   // [512, 50257]
  const float* b      = (const float*)d_in[4];   // [50257]
  float* out = (float*)d_out;

  char* ws = (char*)d_ws;
  unsigned short* Wt     = (unsigned short*)(ws + OFF_WT);
  unsigned short* Xc     = (unsigned short*)(ws + OFF_XC);
  float*          bpad   = (float*)(ws + OFF_BPAD);
  int*            rowidx = (int*)(ws + OFF_ROWIDX);
  float*          that   = (float*)(ws + OFF_THAT);
  unsigned int*   counts = (unsigned int*)(ws + OFF_COUNTS);
  int*            amb    = (int*)(ws + OFF_AMB);
  Ctrl*           ctrl   = (Ctrl*)(ws + OFF_CTRL);
  int*            rk     = (int*)(ws + OFF_RK);
  float*          sst    = (float*)(ws + OFF_SST);

  // zero counts + amb + ctrl + rk (contiguous region)
  hipMemsetAsync(ws + OFF_COUNTS, 0, 32768 + 32768 + 16 + 32768, stream);

  k_prep   <<<197, 256, 0, stream>>>(mask, b, bpad, rowidx, ctrl);
  k_twt    <<<dim3(788, 8), 256, 0, stream>>>(W, Wt);
  k_xc     <<<2048, 256, 0, stream>>>(x, rowidx, ctrl, Xc);
  k_that   <<<2048, 256, 0, stream>>>(Xc, Wt, bpad, rowidx, target, ctrl, that);
  k_count  <<<dim3(NTB, 32), 512, 0, stream>>>(Xc, Wt, bpad, that, ctrl, counts);
  k_decide <<<32, 256, 0, stream>>>(counts, ctrl, amb);
  k_fixt   <<<128, 64, 0, stream>>>(x, W, b, rowidx, target, amb, ctrl, sst);
  k_fixscan<<<197, 256, 0, stream>>>(x, W, b, rowidx, target, amb, sst, ctrl, rk);
  k_fixdec <<<32, 256, 0, stream>>>(rk, ctrl);
  k_final  <<<1, 1, 0, stream>>>(ctrl, out);
}

// Round 7
// 529.705 us; speedup vs baseline: 1.4213x; 1.2618x over previous
//
#include <hip/hip_runtime.h>
#include <stdint.h>

// ---------------------------------------------------------------------------
// Problem constants
// ---------------------------------------------------------------------------
#define V_VOCAB 50257
#define V_PAD   51200          // 400 * 128  (grid 400*64 = 25600 ≡ 0 mod 8)
#define NTB     400            // N tiles of 128
#define NROWS   8192           // 4 * 2048
#define DIM     512
#define KTOP    10
#define MARGIN  0.3f           // >= 2 * (2^-7 * ||x|| * ||w||) worst case (~0.25)
#define ACH     8              // amb rows per W-scan pass

typedef __attribute__((ext_vector_type(8))) short  short8;
typedef __attribute__((ext_vector_type(4))) float  f32x4;

struct Ctrl { int mc; int namb; int hits; int pad_; };

// ws layout (bytes). Total ~61.2 MB.
#define OFF_WT     0ULL
#define SZ_WT      52428800ULL            // 51200*512*2
#define OFF_XC     (OFF_WT + SZ_WT)
#define SZ_XC      8388608ULL             // 8192*512*2
#define OFF_BPAD   (OFF_XC + SZ_XC)
#define SZ_BPAD    (51200ULL*4)
#define OFF_ROWIDX (OFF_BPAD + SZ_BPAD)
#define OFF_THAT   (OFF_ROWIDX + 32768ULL)
#define OFF_COUNTS (OFF_THAT + 32768ULL)
#define OFF_AMB    (OFF_COUNTS + 32768ULL)
#define OFF_CTRL   (OFF_AMB + 32768ULL)
#define OFF_RK     (OFF_CTRL + 16ULL)
#define OFF_SST    (OFF_RK + 32768ULL)

#define GLOAD16(gp, lp) __builtin_amdgcn_global_load_lds( \
    (const __attribute__((address_space(1))) unsigned int*)(gp), \
    (__attribute__((address_space(3))) unsigned int*)(lp), 16, 0, 0)

__device__ __forceinline__ unsigned short f2bf(float f) {
  unsigned int u = __builtin_bit_cast(unsigned int, f);
  unsigned int r = (u + 0x7FFFu + ((u >> 16) & 1u)) >> 16;   // RNE
  return (unsigned short)r;
}
__device__ __forceinline__ float bf2f(unsigned short h) {
  unsigned int u = ((unsigned int)h) << 16;
  return __builtin_bit_cast(float, u);
}

// ---------------------------------------------------------------------------
// 1. prep
// ---------------------------------------------------------------------------
__global__ void k_prep(const int* __restrict__ mask, const float* __restrict__ b,
                       float* __restrict__ bpad, int* __restrict__ rowidx,
                       Ctrl* __restrict__ ctrl) {
  int i = blockIdx.x * 256 + threadIdx.x;
  if (i < V_PAD) bpad[i] = (i < V_VOCAB) ? b[i] : -1e30f;
  if (i < NROWS && mask[i] != 0) {
    int p = atomicAdd(&ctrl->mc, 1);
    rowidx[p] = i;
  }
}

// ---------------------------------------------------------------------------
// 2. transpose+convert: W f32[512][V] -> Wt bf16[V_PAD][512]
// ---------------------------------------------------------------------------
__global__ void k_twt(const float* __restrict__ W, unsigned short* __restrict__ Wt) {
  __shared__ float lt[64][65];
  const int vbase = blockIdx.x * 64;
  const int kbase = blockIdx.y * 64;
  const int tid = threadIdx.x;
  const int krow = tid >> 6;
  const int col  = tid & 63;
  const int v    = vbase + col;
#pragma unroll
  for (int rr = 0; rr < 16; ++rr) {
    int kl = krow + rr * 4;
    float val = (v < V_VOCAB) ? W[(size_t)(kbase + kl) * V_VOCAB + v] : 0.0f;
    lt[kl][col] = val;
  }
  __syncthreads();
  const int vr = tid >> 3;
  const int kc = tid & 7;
#pragma unroll
  for (int p = 0; p < 2; ++p) {
    int vl = p * 32 + vr;
    short8 t;
#pragma unroll
    for (int j = 0; j < 8; ++j) t[j] = (short)f2bf(lt[kc * 8 + j][vl]);
    *(short8*)(Wt + (size_t)(vbase + vl) * DIM + kbase + kc * 8) = t;
  }
}

// ---------------------------------------------------------------------------
// 3. convert compacted x rows to bf16
// ---------------------------------------------------------------------------
__global__ void k_xc(const float* __restrict__ x, const int* __restrict__ rowidx,
                     const Ctrl* __restrict__ ctrl, unsigned short* __restrict__ Xc) {
  const int wid = threadIdx.x >> 6, lane = threadIdx.x & 63;
  const int i = blockIdx.x * 4 + wid;
  const int mc = ctrl->mc;
  short8 t;
  if (i < mc) {
    const float* src = x + (size_t)rowidx[i] * DIM + lane * 8;
#pragma unroll
    for (int j = 0; j < 8; ++j) t[j] = (short)f2bf(src[j]);
  } else {
#pragma unroll
    for (int j = 0; j < 8; ++j) t[j] = 0;
  }
  *(short8*)(Xc + (size_t)i * DIM + lane * 8) = t;
}

// ---------------------------------------------------------------------------
// 4. per-row approx target score t_hat
// ---------------------------------------------------------------------------
__global__ void k_that(const unsigned short* __restrict__ Xc,
                       const unsigned short* __restrict__ Wt,
                       const float* __restrict__ bpad,
                       const int* __restrict__ rowidx, const int* __restrict__ target,
                       const Ctrl* __restrict__ ctrl, float* __restrict__ that) {
  const int wid = threadIdx.x >> 6, lane = threadIdx.x & 63;
  const int i = blockIdx.x * 4 + wid;
  const int mc = ctrl->mc;
  if (i >= mc) { if (lane == 0) that[i] = 1e30f; return; }
  const int tg = target[rowidx[i]];
  short8 xa = *(const short8*)(Xc + (size_t)i * DIM + lane * 8);
  short8 wa = *(const short8*)(Wt + (size_t)tg * DIM + lane * 8);
  float s = 0.f;
#pragma unroll
  for (int j = 0; j < 8; ++j)
    s += bf2f((unsigned short)xa[j]) * bf2f((unsigned short)wa[j]);
#pragma unroll
  for (int d = 1; d < 64; d <<= 1) s += __shfl_xor(s, d, 64);
  if (lane == 0) that[i] = s + bpad[tg];
}

// ---------------------------------------------------------------------------
// 5. fused GEMM-count: R2's proven 128x128/BK=64/4-wave structure +
//    m97-style prefetch (stage kt+1 at iteration top, compute kt, barrier)
//    + double-buffered 64KB LDS (2 blocks/CU) + clean XCD swizzle
//    (xcd = lin&7 gets n-slice [xcd*50, xcd*50+50), m fastest within).
//    XOR slot swizzle via pre-swizzled global source (proven 0-conflict).
//    Compiler-managed waits; no inline asm.
// ---------------------------------------------------------------------------
__launch_bounds__(256, 2)
__global__ void k_count(const unsigned short* __restrict__ Xc,
                        const unsigned short* __restrict__ Wt,
                        const float* __restrict__ bpad, const float* __restrict__ that,
                        const Ctrl* __restrict__ ctrl, unsigned int* __restrict__ counts) {
  const int mc = ctrl->mc;
  // XCD swizzle: 25600 blocks = 8 XCDs x (50 n-tiles x 64 m-tiles)
  const int lin = blockIdx.x;
  const int xcd = lin & 7;
  const int idx = lin >> 3;             // 0..3199
  const int mt  = idx & 63;             // m fastest: B-panel L2-hot per sweep
  const int nt  = xcd * 50 + (idx >> 6);
  const int mbase = mt * 128;
  if (mbase >= mc) return;
  const int nbase = nt * 128;

  __shared__ char lds[65536];           // 2 buffers x (A 16KB + B 16KB)

  const int tid  = threadIdx.x;
  const int lane = tid & 63;
  const int w    = tid >> 6;
  const int wr   = w >> 1;              // 0..1 : A row block (64 rows)
  const int wc   = w & 1;               // 0..1 : B col block (64 cols)

  const char* Ag = (const char*)Xc + (size_t)mbase * 1024;   // row stride 1024B
  const char* Bg = (const char*)Wt + (size_t)nbase * 1024;
  const int r8   = tid >> 3;                                 // 0..31
  const int sws  = ((tid & 7) ^ (r8 & 7)) * 16;              // pre-swizzled src slot
  const int dst0 = tid * 16;

  // stage one K-tile (kt) into buffer q: A 128x64, B 128x64 (4+4 gloads/thread)
#define STAGE(q, kt) do {                                                      \
    const size_t _kb = (size_t)(kt) * 128;                                     \
    _Pragma("unroll") for (int _c = 0; _c < 4; ++_c)                           \
      GLOAD16(Ag + (size_t)(_c * 32 + r8) * 1024 + _kb + sws,                  \
              lds + (q) * 32768 + _c * 4096 + dst0);                           \
    _Pragma("unroll") for (int _c = 0; _c < 4; ++_c)                           \
      GLOAD16(Bg + (size_t)(_c * 32 + r8) * 1024 + _kb + sws,                  \
              lds + (q) * 32768 + 16384 + _c * 4096 + dst0);                   \
  } while (0)

  const int fr = lane & 15;
  const int fq = lane >> 4;
  const int p0 = ((fq) ^ (fr & 7)) * 16;        // phys byte slot, k-slot 0
  const int p1 = ((4 + fq) ^ (fr & 7)) * 16;    // k-slot 1

  f32x4 acc[4][4];
#pragma unroll
  for (int a = 0; a < 4; ++a)
#pragma unroll
    for (int c = 0; c < 4; ++c) acc[a][c] = (f32x4)0.0f;

#define KTILE(q) do {                                                          \
    const char* _ab = lds + (q) * 32768;                                       \
    const char* _bb = _ab + 16384;                                             \
    _Pragma("unroll") for (int _ks = 0; _ks < 2; ++_ks) {                      \
      const int _p = _ks ? p1 : p0;                                            \
      short8 a4[4], b4[4];                                                     \
      _Pragma("unroll") for (int _i = 0; _i < 4; ++_i)                         \
        a4[_i] = *(const short8*)(_ab + (wr * 64 + _i * 16 + fr) * 128 + _p);  \
      _Pragma("unroll") for (int _i = 0; _i < 4; ++_i)                         \
        b4[_i] = *(const short8*)(_bb + (wc * 64 + _i * 16 + fr) * 128 + _p);  \
      __builtin_amdgcn_s_setprio(1);                                           \
      _Pragma("unroll") for (int _m = 0; _m < 4; ++_m)                         \
      _Pragma("unroll") for (int _n = 0; _n < 4; ++_n)                         \
        acc[_m][_n] = __builtin_amdgcn_mfma_f32_16x16x32_bf16(                 \
            a4[_m], b4[_n], acc[_m][_n], 0, 0, 0);                             \
      __builtin_amdgcn_s_setprio(0);                                           \
    }                                                                          \
  } while (0)

  STAGE(0, 0);
  __syncthreads();
#pragma unroll
  for (int kt = 0; kt < 8; ++kt) {
    if (kt < 7) STAGE((kt + 1) & 1, kt + 1);   // prefetch next tile FIRST
    KTILE(kt & 1);                              // compute current
    __syncthreads();                            // drain (m97 structural barrier)
  }

  // epilogue: compare + pack + 16-lane reduce + atomics
  float bv[4];
#pragma unroll
  for (int ni = 0; ni < 4; ++ni)
    bv[ni] = bpad[nbase + wc * 64 + ni * 16 + fr];

#pragma unroll
  for (int mi = 0; mi < 4; ++mi) {
#pragma unroll
    for (int r = 0; r < 4; ++r) {
      const int m = mbase + wr * 64 + mi * 16 + fq * 4 + r;
      const float th  = that[m];
      const float tlo = th - MARGIN, thi = th + MARGIN;
      unsigned int p = 0;
#pragma unroll
      for (int ni = 0; ni < 4; ++ni) {
        const float s = acc[mi][ni][r] + bv[ni];
        p += (s > tlo) ? 1u : 0u;
        p += (s > thi) ? (1u << 16) : 0u;
      }
      int pi = (int)p;
#pragma unroll
      for (int d = 1; d < 16; d <<= 1) pi += __shfl_xor(pi, d, 64);
      if ((lane & 15) == 0) atomicAdd(&counts[m], (unsigned int)pi);
    }
  }
#undef STAGE
#undef KTILE
}

// ---------------------------------------------------------------------------
// 6. decide
// ---------------------------------------------------------------------------
__global__ void k_decide(const unsigned int* __restrict__ counts,
                         Ctrl* __restrict__ ctrl, int* __restrict__ amb) {
  const int i = blockIdx.x * 256 + threadIdx.x;
  if (i >= ctrl->mc) return;
  const unsigned int c = counts[i];
  const unsigned int lo = c & 0xFFFFu, hi = c >> 16;
  if (lo <= KTOP - 1) { atomicAdd(&ctrl->hits, 1); }
  else if (hi >= KTOP) { /* certain miss */ }
  else { int p = atomicAdd(&ctrl->namb, 1); amb[p] = i; }
}

// ---------------------------------------------------------------------------
// 7a. fixup targets (exact f32, sequential fmaf chain — must match k_fixscan)
// ---------------------------------------------------------------------------
__global__ void k_fixt(const float* __restrict__ x, const float* __restrict__ W,
                       const float* __restrict__ b, const int* __restrict__ rowidx,
                       const int* __restrict__ target, const int* __restrict__ amb,
                       const Ctrl* __restrict__ ctrl, float* __restrict__ sst) {
  const int a = blockIdx.x * 64 + threadIdx.x;
  if (a >= ctrl->namb) return;
  const int n = rowidx[amb[a]];
  const int tg = target[n];
  float st = 0.f;
  for (int k = 0; k < DIM; ++k)
    st = fmaf(x[(size_t)n * DIM + k], W[(size_t)k * V_VOCAB + tg], st);
  sst[a] = st + b[tg];
}

// ---------------------------------------------------------------------------
// 7b. fixup scan: one coalesced streaming pass over W for <=ACH rows at a time
// ---------------------------------------------------------------------------
__global__ void k_fixscan(const float* __restrict__ x, const float* __restrict__ W,
                          const float* __restrict__ b, const int* __restrict__ rowidx,
                          const int* __restrict__ target, const int* __restrict__ amb,
                          const float* __restrict__ sst, const Ctrl* __restrict__ ctrl,
                          int* __restrict__ rk) {
  __shared__ float sx[ACH][DIM];
  const int j = blockIdx.x * 256 + threadIdx.x;
  const int namb = ctrl->namb;
  const float bj = (j < V_VOCAB) ? b[j] : 0.f;
  for (int base = 0; base < namb; base += ACH) {
    __syncthreads();
    for (int t = threadIdx.x; t < ACH * DIM / 4; t += 256) {
      const int a  = t / (DIM / 4);
      const int kk = (t % (DIM / 4)) * 4;
      f32x4 v = (f32x4)0.f;
      if (base + a < namb) {
        const int n = rowidx[amb[base + a]];
        v = *(const f32x4*)(x + (size_t)n * DIM + kk);
      }
      *(f32x4*)(&sx[a][kk]) = v;
    }
    __syncthreads();
    if (j >= V_VOCAB) continue;
    float s[ACH];
#pragma unroll
    for (int a = 0; a < ACH; ++a) s[a] = 0.f;
    for (int k = 0; k < DIM; ++k) {
      const float wv = W[(size_t)k * V_VOCAB + j];
#pragma unroll
      for (int a = 0; a < ACH; ++a) s[a] = fmaf(sx[a][k], wv, s[a]);
    }
#pragma unroll
    for (int a = 0; a < ACH; ++a) {
      if (base + a < namb) {
        const int tg = target[rowidx[amb[base + a]]];
        const float sc = s[a] + bj;
        const float st = sst[base + a];
        if (sc > st || (sc == st && j < tg)) atomicAdd(&rk[base + a], 1);
      }
    }
  }
}

// ---------------------------------------------------------------------------
// 7c. fixup decide
// ---------------------------------------------------------------------------
__global__ void k_fixdec(const int* __restrict__ rk, Ctrl* __restrict__ ctrl) {
  const int a = blockIdx.x * 256 + threadIdx.x;
  if (a < ctrl->namb && rk[a] <= KTOP - 1) atomicAdd(&ctrl->hits, 1);
}

// ---------------------------------------------------------------------------
// 8. finalize
// ---------------------------------------------------------------------------
__global__ void k_final(const Ctrl* __restrict__ ctrl, float* __restrict__ out) {
  out[0] = (float)ctrl->hits / (float)ctrl->mc;
}

// ---------------------------------------------------------------------------
extern "C" void kernel_launch(void* const* d_in, const int* in_sizes, int n_in,
                              void* d_out, int out_size, void* d_ws, size_t ws_size,
                              hipStream_t stream) {
  const float* x      = (const float*)d_in[0];   // [8192, 512]
  const int*   target = (const int*)d_in[1];     // [8192]
  const int*   mask   = (const int*)d_in[2];     // [8192]
  const float* W      = (const float*)d_in[3];   // [512, 50257]
  const float* b      = (const float*)d_in[4];   // [50257]
  float* out = (float*)d_out;

  char* ws = (char*)d_ws;
  unsigned short* Wt     = (unsigned short*)(ws + OFF_WT);
  unsigned short* Xc     = (unsigned short*)(ws + OFF_XC);
  float*          bpad   = (float*)(ws + OFF_BPAD);
  int*            rowidx = (int*)(ws + OFF_ROWIDX);
  float*          that   = (float*)(ws + OFF_THAT);
  unsigned int*   counts = (unsigned int*)(ws + OFF_COUNTS);
  int*            amb    = (int*)(ws + OFF_AMB);
  Ctrl*           ctrl   = (Ctrl*)(ws + OFF_CTRL);
  int*            rk     = (int*)(ws + OFF_RK);
  float*          sst    = (float*)(ws + OFF_SST);

  // zero counts + amb + ctrl + rk (contiguous region)
  hipMemsetAsync(ws + OFF_COUNTS, 0, 32768 + 32768 + 16 + 32768, stream);

  k_prep   <<<200, 256, 0, stream>>>(mask, b, bpad, rowidx, ctrl);
  k_twt    <<<dim3(800, 8), 256, 0, stream>>>(W, Wt);
  k_xc     <<<2048, 256, 0, stream>>>(x, rowidx, ctrl, Xc);
  k_that   <<<2048, 256, 0, stream>>>(Xc, Wt, bpad, rowidx, target, ctrl, that);
  k_count  <<<25600, 256, 0, stream>>>(Xc, Wt, bpad, that, ctrl, counts);
  k_decide <<<32, 256, 0, stream>>>(counts, ctrl, amb);
  k_fixt   <<<128, 64, 0, stream>>>(x, W, b, rowidx, target, amb, ctrl, sst);
  k_fixscan<<<197, 256, 0, stream>>>(x, W, b, rowidx, target, amb, sst, ctrl, rk);
  k_fixdec <<<32, 256, 0, stream>>>(rk, ctrl);
  k_final  <<<1, 1, 0, stream>>>(ctrl, out);
}